// Round 13
// baseline (1529.832 us; speedup 1.0000x reference)
//
#include <hip/hip_runtime.h>
#include <hip/hip_bf16.h>
#include <hip/hip_cooperative_groups.h>

namespace cg = cooperative_groups;

#define NN 100000
#define EE 1250000

#define RLF(x, l) __int_as_float(__builtin_amdgcn_readlane(__float_as_int(x), (l)))

__device__ __forceinline__ unsigned short bf16rtn(float x) {
    unsigned u = __float_as_uint(x);
    unsigned r = u + 0x7fffu + ((u >> 16) & 1u);
    return (unsigned short)(r >> 16);
}
__device__ __forceinline__ unsigned bf16rtn2(float lo, float hi) {
    return (unsigned)bf16rtn(lo) | ((unsigned)bf16rtn(hi) << 16);
}
__device__ __forceinline__ float bflo(unsigned u) { return __uint_as_float(u << 16); }
__device__ __forceinline__ float bfhi(unsigned u) { return __uint_as_float(u & 0xffff0000u); }
__device__ __forceinline__ float bfs(unsigned short s) { return __uint_as_float((unsigned)s << 16); }

struct Params {
    const float* x; const int* ei; const float* ew;
    const float* W1; const float* b1; const float* W2; const float* b2;
    const float* W3; const float* b3; const float* W4; const float* b4;
    const float* W5; const float* b5; const float* fW1; const float* fb1;
    const float* fW2; const float* fb2; float* out;
    float* dinv; float* xd; int* rowptr; int* cnt; int* bsum;
    int2* epair; unsigned* Yh; unsigned* Ga; unsigned* Gb; int* slot;
};

// Gather over bf16 rows (R7/R12-proven half-wave shape): one wave per node;
// 16-edge batches = 8 row-loads in flight (2 edges per dword load, wave
// halves); ep indices wave-uniform -> s_load; masked tail clamps to ep[j].
__device__ __forceinline__ void phase_gather(
    const unsigned* __restrict__ G16, const float* __restrict__ dinv,
    const int* __restrict__ rowptr, const int2* __restrict__ ep,
    unsigned* __restrict__ Yh, int bid, int nb, int tid)
{
    int lane = tid & 63, lc = lane & 31, half = lane >> 5, wid = tid >> 6;
    for (int g = bid; g < NN / 4; g += nb) {
        int node = g * 4 + wid;
        int beg = __builtin_amdgcn_readfirstlane(rowptr[node]);
        int end = __builtin_amdgcn_readfirstlane(rowptr[node + 1]);
        float ax = 0.f, ay = 0.f;
        if (half == 0) {
            unsigned u = G16[node * 32 + lc];
            ax = bflo(u); ay = bfhi(u);
        }
        int j = beg;
        for (; j + 16 <= end; j += 16) {
            unsigned u[8]; float nv[8];
            #pragma unroll
            for (int t = 0; t < 8; ++t) {
                int2 pa = ep[j + t];
                int2 pb = ep[j + 8 + t];
                int src = half ? pb.x : pa.x;
                nv[t] = __int_as_float(half ? pb.y : pa.y);
                u[t] = G16[src * 32 + lc];
            }
            #pragma unroll
            for (int t = 0; t < 8; ++t) {
                ax = fmaf(bflo(u[t]), nv[t], ax);
                ay = fmaf(bfhi(u[t]), nv[t], ay);
            }
        }
        if (j < end) {
            unsigned u[8]; float nv[8];
            #pragma unroll
            for (int t = 0; t < 8; ++t) {
                int ia = j + t, ib = j + 8 + t;
                int2 pa = ep[ia < end ? ia : j];
                int2 pb = ep[ib < end ? ib : j];
                int src = half ? pb.x : pa.x;
                float w = __int_as_float(half ? pb.y : pa.y);
                bool v = half ? (ib < end) : (ia < end);
                nv[t] = v ? w : 0.f;
                u[t] = G16[src * 32 + lc];
            }
            #pragma unroll
            for (int t = 0; t < 8; ++t) {
                ax = fmaf(bflo(u[t]), nv[t], ax);
                ay = fmaf(bfhi(u[t]), nv[t], ay);
            }
        }
        ax += __shfl_xor(ax, 32, 64);
        ay += __shfl_xor(ay, 32, 64);
        if (half == 0) {
            float din = dinv[node];
            Yh[node * 32 + lc] = bf16rtn2(din * ax, din * ay);
        }
    }
}

// G' = dinv (.) ( relu(Y + bias) @ W ), W via LDS (4 nodes/wave amortization;
// VGPR-W is demoted in a kernel full of memory loops — R2/R4 lesson).
__device__ __forceinline__ void phase_mv(
    float* sW, const unsigned short* __restrict__ Yh,
    const float* __restrict__ dinv, const float* __restrict__ bias,
    const float* __restrict__ W, unsigned short* __restrict__ Gout,
    int bid, int nb, int tid)
{
    #pragma unroll
    for (int i = 0; i < 16; ++i) sW[tid + i * 256] = W[tid + i * 256];
    __syncthreads();
    int lane = tid & 63, wid = tid >> 6;
    float bl = bias[lane];
    for (int g = bid; g < NN / 16; g += nb) {
        int n0 = (g * 4 + wid) * 4;
        float v0 = fmaxf(bfs(Yh[(n0 + 0) * 64 + lane]) + bl, 0.f);
        float v1 = fmaxf(bfs(Yh[(n0 + 1) * 64 + lane]) + bl, 0.f);
        float v2 = fmaxf(bfs(Yh[(n0 + 2) * 64 + lane]) + bl, 0.f);
        float v3 = fmaxf(bfs(Yh[(n0 + 3) * 64 + lane]) + bl, 0.f);
        float a0 = 0.f, a1 = 0.f, a2 = 0.f, a3 = 0.f;
        #pragma unroll
        for (int k = 0; k < 64; ++k) {
            float wk = sW[k * 64 + lane];
            a0 = fmaf(RLF(v0, k), wk, a0);
            a1 = fmaf(RLF(v1, k), wk, a1);
            a2 = fmaf(RLF(v2, k), wk, a2);
            a3 = fmaf(RLF(v3, k), wk, a3);
        }
        Gout[(n0 + 0) * 64 + lane] = bf16rtn(dinv[n0 + 0] * a0);
        Gout[(n0 + 1) * 64 + lane] = bf16rtn(dinv[n0 + 1] * a1);
        Gout[(n0 + 2) * 64 + lane] = bf16rtn(dinv[n0 + 2] * a2);
        Gout[(n0 + 3) * 64 + lane] = bf16rtn(dinv[n0 + 3] * a3);
    }
}

__global__ __launch_bounds__(256) void k_all(Params P) {
    cg::grid_group grid = cg::this_grid();
    __shared__ float sW[4096];
    __shared__ float sw2[64];
    __shared__ int ls[256];
    __shared__ int sbase;

    const int tid = threadIdx.x;
    const int bid = blockIdx.x;
    const int nb = gridDim.x;
    const int gtid = bid * 256 + tid;
    const int gsz = nb * 256;
    const int lane = tid & 63;
    const int wid = tid >> 6;

    // P0: zero cnt
    for (int i = gtid; i < NN; i += gsz) P.cnt[i] = 0;
    grid.sync();

    // P1: count + slot (1.25M returning atomics — ~23 G/s fabric ceiling)
    for (int e = gtid; e < EE; e += gsz) {
        int d = __builtin_nontemporal_load(&P.ei[EE + e]);
        int s = atomicAdd(&P.cnt[d], 1);
        __builtin_nontemporal_store(s, &P.slot[e]);
    }
    grid.sync();

    // P2: per-1024 block sums
    for (int b = bid; b < 98; b += nb) {
        __syncthreads();
        int base = b * 1024 + tid * 4;
        int s = 0;
        #pragma unroll
        for (int j = 0; j < 4; ++j) { int g = base + j; if (g < NN) s += P.cnt[g]; }
        ls[tid] = s; __syncthreads();
        for (int off = 128; off > 0; off >>= 1) {
            if (tid < off) ls[tid] += ls[tid + off];
            __syncthreads();
        }
        if (tid == 0) P.bsum[b] = ls[0];
    }
    grid.sync();

    // P3: scan -> rowptr (block base from bsum, wave-reduced)
    for (int b = bid; b < 98; b += nb) {
        __syncthreads();
        if (tid < 64) {
            int w0 = (tid < b) ? P.bsum[tid] : 0;
            int w1 = ((64 + tid) < b) ? P.bsum[64 + tid] : 0;
            int s = w0 + w1;
            #pragma unroll
            for (int m = 32; m >= 1; m >>= 1) s += __shfl_xor(s, m, 64);
            if (tid == 0) sbase = s;
        }
        int base = b * 1024 + tid * 4;
        int c[4]; int s = 0;
        #pragma unroll
        for (int j = 0; j < 4; ++j) {
            int g = base + j;
            c[j] = (g < NN) ? P.cnt[g] : 0;
            s += c[j];
        }
        ls[tid] = s; __syncthreads();
        for (int off = 1; off < 256; off <<= 1) {
            int v = (tid >= off) ? ls[tid - off] : 0;
            __syncthreads();
            ls[tid] += v;
            __syncthreads();
        }
        int excl = ls[tid] - s + sbase;
        #pragma unroll
        for (int j = 0; j < 4; ++j) {
            int g = base + j;
            if (g < NN) { P.rowptr[g + 1] = excl + c[j]; excl += c[j]; }
        }
        if (b == 0 && tid == 0) P.rowptr[0] = 0;
    }
    grid.sync();

    // P4: fill packed epair
    for (int e = gtid; e < EE; e += gsz) {
        int s = __builtin_nontemporal_load(&P.ei[e]);
        int d = __builtin_nontemporal_load(&P.ei[EE + e]);
        float w = __builtin_nontemporal_load(&P.ew[e]);
        int sl = __builtin_nontemporal_load(&P.slot[e]);
        P.epair[P.rowptr[d] + sl] = make_int2(s, __float_as_int(w));
    }
    grid.sync();

    // P5: deg -> dinv, xd
    {
        int l16 = lane & 15, sub = lane >> 4;
        for (int g = bid; g < NN / 16; g += nb) {
            int node = (g * 4 + wid) * 4 + sub;
            int beg = P.rowptr[node], end = P.rowptr[node + 1];
            float s = 0.f;
            for (int idx = beg + l16; idx < end; idx += 16)
                s += __int_as_float(P.epair[idx].y);
            #pragma unroll
            for (int m = 8; m >= 1; m >>= 1) s += __shfl_xor(s, m, 64);
            if (l16 == 0) {
                float di = rsqrtf(s + 1.0f);
                P.dinv[node] = di;
                P.xd[node] = di * P.x[node];
            }
        }
    }
    grid.sync();

    // P6: layer 1 (scalar gather + matvec via LDS W2) -> Ga
    {
        #pragma unroll
        for (int i = 0; i < 16; ++i) sW[tid + i * 256] = P.W2[tid + i * 256];
        __syncthreads();
        int l16 = lane & 15, sub = lane >> 4;
        float w1l = P.W1[lane], b1l = P.b1[lane];
        unsigned short* Gout = (unsigned short*)P.Ga;
        for (int g = bid; g < NN / 16; g += nb) {
            int g4 = g * 4 + wid;
            int nodeS = g4 * 4 + sub;
            int beg = P.rowptr[nodeS], end = P.rowptr[nodeS + 1];
            float partial = 0.f;
            for (int idx = beg + l16; idx < end; idx += 16) {
                int2 p = P.epair[idx];
                partial = fmaf(__int_as_float(p.y), P.xd[p.x], partial);
            }
            #pragma unroll
            for (int m = 8; m >= 1; m >>= 1) partial += __shfl_xor(partial, m, 64);
            float z = P.dinv[nodeS] * (P.xd[nodeS] + partial);
            float z0 = RLF(z, 0), z1 = RLF(z, 16), z2 = RLF(z, 32), z3 = RLF(z, 48);
            float v0 = fmaxf(fmaf(z0, w1l, b1l), 0.f);
            float v1 = fmaxf(fmaf(z1, w1l, b1l), 0.f);
            float v2 = fmaxf(fmaf(z2, w1l, b1l), 0.f);
            float v3 = fmaxf(fmaf(z3, w1l, b1l), 0.f);
            float a0 = 0.f, a1 = 0.f, a2 = 0.f, a3 = 0.f;
            #pragma unroll
            for (int k = 0; k < 64; ++k) {
                float wk = sW[k * 64 + lane];
                a0 = fmaf(RLF(v0, k), wk, a0);
                a1 = fmaf(RLF(v1, k), wk, a1);
                a2 = fmaf(RLF(v2, k), wk, a2);
                a3 = fmaf(RLF(v3, k), wk, a3);
            }
            int n0 = g4 * 4;
            Gout[(n0 + 0) * 64 + lane] = bf16rtn(P.dinv[n0 + 0] * a0);
            Gout[(n0 + 1) * 64 + lane] = bf16rtn(P.dinv[n0 + 1] * a1);
            Gout[(n0 + 2) * 64 + lane] = bf16rtn(P.dinv[n0 + 2] * a2);
            Gout[(n0 + 3) * 64 + lane] = bf16rtn(P.dinv[n0 + 3] * a3);
        }
    }
    grid.sync();

    // Layers 2..4: gather -> mv
    phase_gather(P.Ga, P.dinv, P.rowptr, P.epair, P.Yh, bid, nb, tid);
    grid.sync();
    phase_mv(sW, (const unsigned short*)P.Yh, P.dinv, P.b2, P.W3,
             (unsigned short*)P.Gb, bid, nb, tid);
    grid.sync();
    phase_gather(P.Gb, P.dinv, P.rowptr, P.epair, P.Yh, bid, nb, tid);
    grid.sync();
    phase_mv(sW, (const unsigned short*)P.Yh, P.dinv, P.b3, P.W4,
             (unsigned short*)P.Ga, bid, nb, tid);
    grid.sync();
    phase_gather(P.Ga, P.dinv, P.rowptr, P.epair, P.Yh, bid, nb, tid);
    grid.sync();
    phase_mv(sW, (const unsigned short*)P.Yh, P.dinv, P.b4, P.W5,
             (unsigned short*)P.Gb, bid, nb, tid);
    grid.sync();
    // Layer 5 gather + head
    phase_gather(P.Gb, P.dinv, P.rowptr, P.epair, P.Yh, bid, nb, tid);
    grid.sync();
    {
        #pragma unroll
        for (int i = 0; i < 16; ++i) sW[tid + i * 256] = P.fW1[tid + i * 256];
        if (tid < 64) sw2[tid] = P.fW2[tid];
        __syncthreads();
        const unsigned short* Yh16 = (const unsigned short*)P.Yh;
        float bl = P.b5[lane], fb1l = P.fb1[lane], fb2s = P.fb2[0];
        for (int g = bid; g < NN / 16; g += nb) {
            int n0 = (g * 4 + wid) * 4;
            float v0 = fmaxf(bfs(Yh16[(n0 + 0) * 64 + lane]) + bl, 0.f);
            float v1 = fmaxf(bfs(Yh16[(n0 + 1) * 64 + lane]) + bl, 0.f);
            float v2 = fmaxf(bfs(Yh16[(n0 + 2) * 64 + lane]) + bl, 0.f);
            float v3 = fmaxf(bfs(Yh16[(n0 + 3) * 64 + lane]) + bl, 0.f);
            float a0 = 0.f, a1 = 0.f, a2 = 0.f, a3 = 0.f;
            #pragma unroll
            for (int k = 0; k < 64; ++k) {
                float wk = sW[k * 64 + lane];
                a0 = fmaf(RLF(v0, k), wk, a0);
                a1 = fmaf(RLF(v1, k), wk, a1);
                a2 = fmaf(RLF(v2, k), wk, a2);
                a3 = fmaf(RLF(v3, k), wk, a3);
            }
            float fw2l = sw2[lane];
            float t0 = fmaxf(a0 + fb1l, 0.f) * fw2l;
            float t1 = fmaxf(a1 + fb1l, 0.f) * fw2l;
            float t2 = fmaxf(a2 + fb1l, 0.f) * fw2l;
            float t3 = fmaxf(a3 + fb1l, 0.f) * fw2l;
            #pragma unroll
            for (int m = 32; m >= 1; m >>= 1) {
                t0 += __shfl_xor(t0, m, 64);
                t1 += __shfl_xor(t1, m, 64);
                t2 += __shfl_xor(t2, m, 64);
                t3 += __shfl_xor(t3, m, 64);
            }
            if (lane == 0) {
                P.out[n0 + 0] = t0 + fb2s;
                P.out[n0 + 1] = t1 + fb2s;
                P.out[n0 + 2] = t2 + fb2s;
                P.out[n0 + 3] = t3 + fb2s;
            }
        }
    }
}

// ---------------- Launch ----------------

extern "C" void kernel_launch(void* const* d_in, const int* in_sizes, int n_in,
                              void* d_out, int out_size, void* d_ws, size_t ws_size,
                              hipStream_t stream) {
    Params p;
    p.x   = (const float*)d_in[0];
    p.ei  = (const int*)d_in[1];
    p.ew  = (const float*)d_in[2];
    p.W1  = (const float*)d_in[3];
    p.b1  = (const float*)d_in[4];
    p.W2  = (const float*)d_in[5];
    p.b2  = (const float*)d_in[6];
    p.W3  = (const float*)d_in[7];
    p.b3  = (const float*)d_in[8];
    p.W4  = (const float*)d_in[9];
    p.b4  = (const float*)d_in[10];
    p.W5  = (const float*)d_in[11];
    p.b5  = (const float*)d_in[12];
    p.fW1 = (const float*)d_in[13];
    p.fb1 = (const float*)d_in[14];
    p.fW2 = (const float*)d_in[15];
    p.fb2 = (const float*)d_in[16];
    p.out = (float*)d_out;

    char* ws = (char*)d_ws;
    size_t o = 0;
    auto alloc = [&](size_t elems) -> void* {
        void* q = (void*)(ws + o);
        o += ((elems * 4 + 255) / 256) * 256;
        return q;
    };
    p.dinv   = (float*)alloc(NN);
    p.xd     = (float*)alloc(NN);
    p.rowptr = (int*)alloc(NN + 1);
    p.cnt    = (int*)alloc(NN);
    p.bsum   = (int*)alloc(128);
    p.epair  = (int2*)alloc(2 * (size_t)EE);
    p.Yh     = (unsigned*)alloc((size_t)NN * 32);
    p.Ga     = (unsigned*)alloc((size_t)NN * 32);
    p.Gb     = (unsigned*)alloc((size_t)NN * 32);
    p.slot   = (int*)alloc(EE);

    int nblk = 0;
    hipError_t err = hipOccupancyMaxActiveBlocksPerMultiprocessor(&nblk, k_all, 256, 0);
    if (err != hipSuccess || nblk < 1) nblk = 4;
    if (nblk > 8) nblk = 8;
    int grid = nblk * 256;   // 256 CUs on MI355X; co-resident by construction

    void* args[] = { (void*)&p };
    hipLaunchCooperativeKernel((const void*)k_all, dim3(grid), dim3(256),
                               args, 0, stream);
}

// Round 14
// 906.042 us; speedup vs baseline: 1.6885x; 1.6885x over previous
//
#include <hip/hip_runtime.h>
#include <hip/hip_bf16.h>

#define NN 100000
#define EE 1250000

#define RLF(x, l) __int_as_float(__builtin_amdgcn_readlane(__float_as_int(x), (l)))

__device__ __forceinline__ unsigned short bf16rtn(float x) {
    unsigned u = __float_as_uint(x);
    unsigned r = u + 0x7fffu + ((u >> 16) & 1u);
    return (unsigned short)(r >> 16);
}
__device__ __forceinline__ unsigned bf16rtn2(float lo, float hi) {
    return (unsigned)bf16rtn(lo) | ((unsigned)bf16rtn(hi) << 16);
}
__device__ __forceinline__ float bflo(unsigned u) { return __uint_as_float(u << 16); }
__device__ __forceinline__ float bfhi(unsigned u) { return __uint_as_float(u & 0xffff0000u); }

// Quartered bf16 feature layout: quarter q (features 16q..16q+15) is a
// contiguous 3.2 MB slab: uint index q*NN*8 + node*8 + p, uint p packing
// features 16q+2p (lo) / 16q+2p+1 (hi). 3.2 MB < 4 MB per-XCD L2.
__device__ __forceinline__ float qreadY(const unsigned* __restrict__ Yh, int node, int lane) {
    unsigned u = Yh[(size_t)(lane >> 4) * (NN * 8) + (size_t)node * 8 + ((lane & 15) >> 1)];
    return (lane & 1) ? bfhi(u) : bflo(u);
}
__device__ __forceinline__ size_t qidx16(int node, int lane) {   // ushort index for feat store
    return (size_t)(lane >> 4) * ((size_t)NN * 16) + (size_t)node * 16 + (lane & 15);
}

// ---------------- CSR build (packed; R9/R12-proven) ----------------
// Atomic pass: ~23 G returning atomics/s fabric ceiling, ~50us floor.

__global__ __launch_bounds__(256) void k_count(const int* __restrict__ ei,
                                               int* __restrict__ cnt,
                                               int* __restrict__ slot) {
    int e = blockIdx.x * 256 + threadIdx.x;
    if (e >= EE) return;
    int d = __builtin_nontemporal_load(&ei[EE + e]);
    int s = atomicAdd(&cnt[d], 1);
    __builtin_nontemporal_store(s, &slot[e]);
}

__global__ __launch_bounds__(256) void k_bsum(const int* __restrict__ cnt, int* __restrict__ bsum) {
    __shared__ int ls[256];
    int b = blockIdx.x, tid = threadIdx.x;
    int base = b * 1024 + tid * 4;
    int s = 0;
    #pragma unroll
    for (int j = 0; j < 4; ++j) { int g = base + j; if (g < NN) s += cnt[g]; }
    ls[tid] = s; __syncthreads();
    for (int off = 128; off > 0; off >>= 1) {
        if (tid < off) ls[tid] += ls[tid + off];
        __syncthreads();
    }
    if (tid == 0) bsum[b] = ls[0];
}

__global__ __launch_bounds__(256) void k_scan_out(const int* __restrict__ cnt,
                                                  const int* __restrict__ bsum,
                                                  int* __restrict__ rowptr) {
    __shared__ int ls[256];
    __shared__ int sbase;
    int b = blockIdx.x, tid = threadIdx.x;
    if (tid < 64) {
        int w0 = (tid < b) ? bsum[tid] : 0;
        int w1 = ((64 + tid) < b) ? bsum[64 + tid] : 0;
        int s = w0 + w1;
        #pragma unroll
        for (int m = 32; m >= 1; m >>= 1) s += __shfl_xor(s, m, 64);
        if (tid == 0) sbase = s;
    }
    int base = b * 1024 + tid * 4;
    int c[4]; int s = 0;
    #pragma unroll
    for (int j = 0; j < 4; ++j) {
        int g = base + j;
        c[j] = (g < NN) ? cnt[g] : 0;
        s += c[j];
    }
    ls[tid] = s; __syncthreads();
    for (int off = 1; off < 256; off <<= 1) {
        int v = (tid >= off) ? ls[tid - off] : 0;
        __syncthreads();
        ls[tid] += v;
        __syncthreads();
    }
    int excl = ls[tid] - s + sbase;
    #pragma unroll
    for (int j = 0; j < 4; ++j) {
        int g = base + j;
        if (g < NN) {
            rowptr[g + 1] = excl + c[j];
            excl += c[j];
        }
    }
    if (b == 0 && tid == 0) rowptr[0] = 0;
}

__global__ __launch_bounds__(256) void k_fill(const int* __restrict__ ei,
                                              const float* __restrict__ ew,
                                              const int* __restrict__ slot,
                                              const int* __restrict__ rowptr,
                                              int2* __restrict__ epair) {
    int e = blockIdx.x * 256 + threadIdx.x;
    if (e >= EE) return;
    int s = __builtin_nontemporal_load(&ei[e]);
    int d = __builtin_nontemporal_load(&ei[EE + e]);
    float w = __builtin_nontemporal_load(&ew[e]);
    int sl = __builtin_nontemporal_load(&slot[e]);
    int p = rowptr[d] + sl;
    epair[p] = make_int2(s, __float_as_int(w));
}

// deg[n] = 1 + sum_row ew -> dinv[n], xd[n] = dinv[n]*x[n].  4 nodes/wave.
__global__ __launch_bounds__(256) void k_deg(const int* __restrict__ rowptr,
                                             const int2* __restrict__ epair,
                                             const float* __restrict__ x,
                                             float* __restrict__ dinv,
                                             float* __restrict__ xd) {
    int lane = threadIdx.x & 63;
    int wid  = threadIdx.x >> 6;
    int l16  = lane & 15;
    int sub  = lane >> 4;
    int node = (blockIdx.x * 4 + wid) * 4 + sub;
    if (node >= NN) return;
    int beg = rowptr[node], end = rowptr[node + 1];
    float s = 0.f;
    for (int idx = beg + l16; idx < end; idx += 16)
        s += __int_as_float(epair[idx].y);
    #pragma unroll
    for (int m = 8; m >= 1; m >>= 1) s += __shfl_xor(s, m, 64);
    if (l16 == 0) {
        float di = rsqrtf(s + 1.0f);
        dinv[node] = di;
        xd[node] = di * x[node];
    }
}

// ---------------- Layers ----------------
// Identity: Agg_l[d] = dinv_d * ( G'_l[d] + sum_e w_e * G'_l[src] ), G' = dinv (.) G.
// G' and Y stored bf16 in the QUARTERED layout. Accumulation fp32.

// Layer 1: z scalar agg + matvec, W2 via LDS. grid NN/16. Quartered store.
__global__ __launch_bounds__(256) void k_l1(
    const float* __restrict__ xd, const float* __restrict__ dinv,
    const int* __restrict__ rowptr, const int2* __restrict__ ep,
    const float* __restrict__ W1, const float* __restrict__ b1,
    const float* __restrict__ W2, unsigned short* __restrict__ Gout)
{
    __shared__ float sW[4096];
    int tid = threadIdx.x;
    #pragma unroll
    for (int i = 0; i < 16; ++i) sW[tid + i * 256] = W2[tid + i * 256];
    __syncthreads();
    int lane = tid & 63, l16 = lane & 15, sub = lane >> 4;
    int g4 = blockIdx.x * 4 + (tid >> 6);
    int nodeS = g4 * 4 + sub;
    int beg = rowptr[nodeS], end = rowptr[nodeS + 1];
    float partial = 0.f;
    for (int idx = beg + l16; idx < end; idx += 16) {
        int2 p = ep[idx];
        partial = fmaf(__int_as_float(p.y), xd[p.x], partial);
    }
    #pragma unroll
    for (int m = 8; m >= 1; m >>= 1) partial += __shfl_xor(partial, m, 64);
    float z = dinv[nodeS] * (xd[nodeS] + partial);   // valid where l16==0
    float z0 = RLF(z, 0), z1 = RLF(z, 16), z2 = RLF(z, 32), z3 = RLF(z, 48);
    float w1l = W1[lane], b1l = b1[lane];
    float v0 = fmaxf(fmaf(z0, w1l, b1l), 0.f);
    float v1 = fmaxf(fmaf(z1, w1l, b1l), 0.f);
    float v2 = fmaxf(fmaf(z2, w1l, b1l), 0.f);
    float v3 = fmaxf(fmaf(z3, w1l, b1l), 0.f);
    float a0 = 0.f, a1 = 0.f, a2 = 0.f, a3 = 0.f;
    #pragma unroll
    for (int k = 0; k < 64; ++k) {
        float wk = sW[k * 64 + lane];
        a0 = fmaf(RLF(v0, k), wk, a0);
        a1 = fmaf(RLF(v1, k), wk, a1);
        a2 = fmaf(RLF(v2, k), wk, a2);
        a3 = fmaf(RLF(v3, k), wk, a3);
    }
    int n0 = g4 * 4;
    Gout[qidx16(n0 + 0, lane)] = bf16rtn(dinv[n0 + 0] * a0);
    Gout[qidx16(n0 + 1, lane)] = bf16rtn(dinv[n0 + 1] * a1);
    Gout[qidx16(n0 + 2, lane)] = bf16rtn(dinv[n0 + 2] * a2);
    Gout[qidx16(n0 + 3, lane)] = bf16rtn(dinv[n0 + 3] * a3);
}

// Quartered gather: Y[d] = dinv_d * ( G'[d] + sum_e w_e * G'[src] ), one
// feature-quarter per block, quarter pinned to XCD pair via blockIdx&7
// (blocks round-robin across 8 XCDs) so each XCD's L2 holds one 3.2 MB slab.
// Wave = 1 node: 8 lanes per 32B quarter-row -> 8 edges per load inst; src &
// weight selected from 8 wave-uniform scalars (s_load) by a cndmask tree;
// tail masked by scalar weight=0. grid = NN blocks (4 quarters x NN/4).
__global__ __launch_bounds__(256) void k_gather(
    const unsigned* __restrict__ G16, const float* __restrict__ dinv,
    const int* __restrict__ rowptr, const int2* __restrict__ ep,
    unsigned* __restrict__ Yh)
{
    int tid = threadIdx.x;
    int bid = blockIdx.x;
    int q  = (bid & 7) >> 1;                    // quarter = XCD pair
    int jb = (bid >> 3) * 2 + (bid & 1);        // 0..NN/4-1
    int node = jb * 4 + (tid >> 6);
    int lane = tid & 63;
    int g = lane >> 3;                          // edge slot 0..7
    int p = lane & 7;                           // uint within quarter row
    const unsigned* Gq = G16 + (size_t)q * (NN * 8);
    unsigned* Yq = Yh + (size_t)q * (NN * 8);
    int beg = __builtin_amdgcn_readfirstlane(rowptr[node]);
    int end = __builtin_amdgcn_readfirstlane(rowptr[node + 1]);
    unsigned selfu = Gq[(size_t)node * 8 + p];
    float ax = (g == 0) ? bflo(selfu) : 0.f;
    float ay = (g == 0) ? bfhi(selfu) : 0.f;

    int j = beg;
    for (; j + 16 <= end; j += 16) {            // full batch: 16 edges, 2 loads
        unsigned u[2]; float wv[2];
        #pragma unroll
        for (int b = 0; b < 2; ++b) {
            int base = j + b * 8;
            int2 e0 = ep[base + 0], e1 = ep[base + 1], e2 = ep[base + 2], e3 = ep[base + 3];
            int2 e4 = ep[base + 4], e5 = ep[base + 5], e6 = ep[base + 6], e7 = ep[base + 7];
            int a0 = (g & 1) ? e1.x : e0.x;
            int a1 = (g & 1) ? e3.x : e2.x;
            int a2 = (g & 1) ? e5.x : e4.x;
            int a3 = (g & 1) ? e7.x : e6.x;
            int b0 = (g & 2) ? a1 : a0;
            int b1 = (g & 2) ? a3 : a2;
            int src = (g & 4) ? b1 : b0;
            int c0 = (g & 1) ? e1.y : e0.y;
            int c1 = (g & 1) ? e3.y : e2.y;
            int c2 = (g & 1) ? e5.y : e4.y;
            int c3 = (g & 1) ? e7.y : e6.y;
            int d0 = (g & 2) ? c1 : c0;
            int d1 = (g & 2) ? c3 : c2;
            wv[b] = __int_as_float((g & 4) ? d1 : d0);
            u[b] = Gq[(size_t)src * 8 + p];
        }
        #pragma unroll
        for (int b = 0; b < 2; ++b) {
            ax = fmaf(bflo(u[b]), wv[b], ax);
            ay = fmaf(bfhi(u[b]), wv[b], ay);
        }
    }
    if (j < end) {                              // masked batch (tail 1..15)
        unsigned u[2]; float wv[2];
        #pragma unroll
        for (int b = 0; b < 2; ++b) {
            int base = j + b * 8;
            int2 ee[8];
            #pragma unroll
            for (int k = 0; k < 8; ++k) {
                int idx = base + k;                 // uniform
                int2 e = ep[idx < end ? idx : beg]; // scalar clamp
                if (!(idx < end)) e.y = 0;          // scalar weight mask
                ee[k] = e;
            }
            int a0 = (g & 1) ? ee[1].x : ee[0].x;
            int a1 = (g & 1) ? ee[3].x : ee[2].x;
            int a2 = (g & 1) ? ee[5].x : ee[4].x;
            int a3 = (g & 1) ? ee[7].x : ee[6].x;
            int b0 = (g & 2) ? a1 : a0;
            int b1 = (g & 2) ? a3 : a2;
            int src = (g & 4) ? b1 : b0;
            int c0 = (g & 1) ? ee[1].y : ee[0].y;
            int c1 = (g & 1) ? ee[3].y : ee[2].y;
            int c2 = (g & 1) ? ee[5].y : ee[4].y;
            int c3 = (g & 1) ? ee[7].y : ee[6].y;
            int d0 = (g & 2) ? c1 : c0;
            int d1 = (g & 2) ? c3 : c2;
            wv[b] = __int_as_float((g & 4) ? d1 : d0);
            u[b] = Gq[(size_t)src * 8 + p];
        }
        #pragma unroll
        for (int b = 0; b < 2; ++b) {
            ax = fmaf(bflo(u[b]), wv[b], ax);
            ay = fmaf(bfhi(u[b]), wv[b], ay);
        }
    }
    // reduce over edge slots (stride-8 lanes share a feature pair)
    #pragma unroll
    for (int m = 8; m <= 32; m <<= 1) {
        ax += __shfl_xor(ax, m, 64);
        ay += __shfl_xor(ay, m, 64);
    }
    if (g == 0) {
        float din = dinv[node];
        Yq[(size_t)node * 8 + p] = bf16rtn2(din * ax, din * ay);
    }
}

// G' = dinv (.) ( relu(Y + bias) @ W ), quartered bf16 in/out — 4 nodes/wave,
// W in VGPRs (no preceding memory loop -> safe from demotion). grid NN/16.
__global__ __launch_bounds__(256, 4) void k_mv(
    const unsigned* __restrict__ Yh, const float* __restrict__ dinv,
    const float* __restrict__ bias, const float* __restrict__ W,
    unsigned short* __restrict__ Gout)
{
    int lane = threadIdx.x & 63;
    int wid  = threadIdx.x >> 6;
    float w[64];
    #pragma unroll
    for (int k = 0; k < 64; ++k) w[k] = W[k * 64 + lane];
    float bl = bias[lane];
    int n0 = (blockIdx.x * 4 + wid) * 4;
    float v0 = fmaxf(qreadY(Yh, n0 + 0, lane) + bl, 0.f);
    float v1 = fmaxf(qreadY(Yh, n0 + 1, lane) + bl, 0.f);
    float v2 = fmaxf(qreadY(Yh, n0 + 2, lane) + bl, 0.f);
    float v3 = fmaxf(qreadY(Yh, n0 + 3, lane) + bl, 0.f);
    float a0 = 0.f, a1 = 0.f, a2 = 0.f, a3 = 0.f;
    #pragma unroll
    for (int k = 0; k < 64; ++k) {
        float wk = w[k];
        a0 = fmaf(RLF(v0, k), wk, a0);
        a1 = fmaf(RLF(v1, k), wk, a1);
        a2 = fmaf(RLF(v2, k), wk, a2);
        a3 = fmaf(RLF(v3, k), wk, a3);
    }
    Gout[qidx16(n0 + 0, lane)] = bf16rtn(dinv[n0 + 0] * a0);
    Gout[qidx16(n0 + 1, lane)] = bf16rtn(dinv[n0 + 1] * a1);
    Gout[qidx16(n0 + 2, lane)] = bf16rtn(dinv[n0 + 2] * a2);
    Gout[qidx16(n0 + 3, lane)] = bf16rtn(dinv[n0 + 3] * a3);
}

// out = relu(relu(Y+b5)@fW1 + fb1) @ fW2 + fb2 — 4 nodes/wave, fW1 in VGPRs. grid NN/16.
__global__ __launch_bounds__(256, 4) void k_head(
    const unsigned* __restrict__ Yh, const float* __restrict__ b5,
    const float* __restrict__ fW1, const float* __restrict__ fb1,
    const float* __restrict__ fW2, const float* __restrict__ fb2,
    float* __restrict__ out)
{
    int lane = threadIdx.x & 63;
    int wid  = threadIdx.x >> 6;
    float w[64];
    #pragma unroll
    for (int k = 0; k < 64; ++k) w[k] = fW1[k * 64 + lane];
    float bl = b5[lane], fb1l = fb1[lane], fw2l = fW2[lane], fb2s = fb2[0];
    int n0 = (blockIdx.x * 4 + wid) * 4;
    float v0 = fmaxf(qreadY(Yh, n0 + 0, lane) + bl, 0.f);
    float v1 = fmaxf(qreadY(Yh, n0 + 1, lane) + bl, 0.f);
    float v2 = fmaxf(qreadY(Yh, n0 + 2, lane) + bl, 0.f);
    float v3 = fmaxf(qreadY(Yh, n0 + 3, lane) + bl, 0.f);
    float a0 = 0.f, a1 = 0.f, a2 = 0.f, a3 = 0.f;
    #pragma unroll
    for (int k = 0; k < 64; ++k) {
        float wk = w[k];
        a0 = fmaf(RLF(v0, k), wk, a0);
        a1 = fmaf(RLF(v1, k), wk, a1);
        a2 = fmaf(RLF(v2, k), wk, a2);
        a3 = fmaf(RLF(v3, k), wk, a3);
    }
    float t0 = fmaxf(a0 + fb1l, 0.f) * fw2l;
    float t1 = fmaxf(a1 + fb1l, 0.f) * fw2l;
    float t2 = fmaxf(a2 + fb1l, 0.f) * fw2l;
    float t3 = fmaxf(a3 + fb1l, 0.f) * fw2l;
    #pragma unroll
    for (int m = 32; m >= 1; m >>= 1) {
        t0 += __shfl_xor(t0, m, 64);
        t1 += __shfl_xor(t1, m, 64);
        t2 += __shfl_xor(t2, m, 64);
        t3 += __shfl_xor(t3, m, 64);
    }
    if (lane == 0) {
        out[n0 + 0] = t0 + fb2s;
        out[n0 + 1] = t1 + fb2s;
        out[n0 + 2] = t2 + fb2s;
        out[n0 + 3] = t3 + fb2s;
    }
}

// ---------------- Launch ----------------

extern "C" void kernel_launch(void* const* d_in, const int* in_sizes, int n_in,
                              void* d_out, int out_size, void* d_ws, size_t ws_size,
                              hipStream_t stream) {
    const float* x   = (const float*)d_in[0];
    const int*   ei  = (const int*)d_in[1];
    const float* ew  = (const float*)d_in[2];
    const float* W1  = (const float*)d_in[3];
    const float* b1  = (const float*)d_in[4];
    const float* W2  = (const float*)d_in[5];
    const float* b2  = (const float*)d_in[6];
    const float* W3  = (const float*)d_in[7];
    const float* b3  = (const float*)d_in[8];
    const float* W4  = (const float*)d_in[9];
    const float* b4  = (const float*)d_in[10];
    const float* W5  = (const float*)d_in[11];
    const float* b5  = (const float*)d_in[12];
    const float* fW1 = (const float*)d_in[13];
    const float* fb1 = (const float*)d_in[14];
    const float* fW2 = (const float*)d_in[15];
    const float* fb2 = (const float*)d_in[16];
    float* out = (float*)d_out;

    char* ws = (char*)d_ws;
    size_t o = 0;
    auto alloc = [&](size_t elems) -> void* {
        void* p = (void*)(ws + o);
        o += ((elems * 4 + 255) / 256) * 256;
        return p;
    };
    float* dinv   = (float*)alloc(NN);
    float* xd     = (float*)alloc(NN);
    int*   rowptr = (int*)alloc(NN + 1);
    int*   cnt    = (int*)alloc(NN);
    int*   bsum   = (int*)alloc(128);
    int2*  epair  = (int2*)alloc(2 * (size_t)EE);
    unsigned* Yh   = (unsigned*)alloc((size_t)NN * 32);   // quartered bf16 Y
    unsigned* Ga16 = (unsigned*)alloc((size_t)NN * 32);   // quartered bf16 G
    unsigned* Gb16 = (unsigned*)alloc((size_t)NN * 32);
    int*   slot   = (int*)alloc(EE);

    int gE  = (EE + 255) / 256;
    int nb  = (NN + 1023) / 1024;    // 98
    int gQ  = NN;                    // 100000: quartered gather (4 x NN/4)
    int gW4 = NN / 16;               // 6250:  4 nodes/wave

    hipMemsetAsync(cnt, 0, NN * sizeof(int), stream);
    k_count<<<gE, 256, 0, stream>>>(ei, cnt, slot);
    k_bsum<<<nb, 256, 0, stream>>>(cnt, bsum);
    k_scan_out<<<nb, 256, 0, stream>>>(cnt, bsum, rowptr);
    k_fill<<<gE, 256, 0, stream>>>(ei, ew, slot, rowptr, epair);
    k_deg<<<gW4, 256, 0, stream>>>(rowptr, epair, x, dinv, xd);

    // Layer 1 (scalar gather + matvec) -> Ga (quartered bf16)
    k_l1<<<gW4, 256, 0, stream>>>(xd, dinv, rowptr, epair, W1, b1, W2,
                                  (unsigned short*)Ga16);
    // Layers 2..4
    k_gather<<<gQ, 256, 0, stream>>>(Ga16, dinv, rowptr, epair, Yh);
    k_mv<<<gW4, 256, 0, stream>>>(Yh, dinv, b2, W3, (unsigned short*)Gb16);
    k_gather<<<gQ, 256, 0, stream>>>(Gb16, dinv, rowptr, epair, Yh);
    k_mv<<<gW4, 256, 0, stream>>>(Yh, dinv, b3, W4, (unsigned short*)Ga16);
    k_gather<<<gQ, 256, 0, stream>>>(Ga16, dinv, rowptr, epair, Yh);
    k_mv<<<gW4, 256, 0, stream>>>(Yh, dinv, b4, W5, (unsigned short*)Gb16);
    // Layer 5 + head
    k_gather<<<gQ, 256, 0, stream>>>(Gb16, dinv, rowptr, epair, Yh);
    k_head<<<gW4, 256, 0, stream>>>(Yh, b5, fW1, fb1, fW2, fb2, out);
}

// Round 16
// 507.772 us; speedup vs baseline: 3.0128x; 1.7843x over previous
//
#include <hip/hip_runtime.h>
#include <hip/hip_bf16.h>

#define NN 100000
#define EE 1250000

#define RL(x, l) __builtin_amdgcn_readlane((x), (l))
#define RLF(x, l) __int_as_float(__builtin_amdgcn_readlane(__float_as_int(x), (l)))

__device__ __forceinline__ unsigned short bf16rtn(float x) {
    unsigned u = __float_as_uint(x);
    unsigned r = u + 0x7fffu + ((u >> 16) & 1u);
    return (unsigned short)(r >> 16);
}
__device__ __forceinline__ unsigned bf16rtn2(float lo, float hi) {
    return (unsigned)bf16rtn(lo) | ((unsigned)bf16rtn(hi) << 16);
}
__device__ __forceinline__ float bflo(unsigned u) { return __uint_as_float(u << 16); }
__device__ __forceinline__ float bfhi(unsigned u) { return __uint_as_float(u & 0xffff0000u); }
__device__ __forceinline__ float bfs(unsigned short s) { return __uint_as_float((unsigned)s << 16); }

// ---------------- CSR build (packed; R9/R12-proven) ----------------
// Atomic pass: ~23 G returning atomics/s fabric ceiling (R2/R5/R9/R10), ~50us
// floor. Measured dead ends: counter padding (R7 null), padded rows (R10
// regression), fused count+fill (R10 regression), cooperative mega-kernel
// (R13: grid.sync ~100us each on 8-XCD), feature-quartered gather (R14:
// VGPR demotion + %8 XCD pinning falsified).

__global__ __launch_bounds__(256) void k_count(const int* __restrict__ ei,
                                               int* __restrict__ cnt,
                                               int* __restrict__ slot) {
    int e = blockIdx.x * 256 + threadIdx.x;
    if (e >= EE) return;
    int d = __builtin_nontemporal_load(&ei[EE + e]);
    int s = atomicAdd(&cnt[d], 1);
    __builtin_nontemporal_store(s, &slot[e]);
}

__global__ __launch_bounds__(256) void k_bsum(const int* __restrict__ cnt, int* __restrict__ bsum) {
    __shared__ int ls[256];
    int b = blockIdx.x, tid = threadIdx.x;
    int base = b * 1024 + tid * 4;
    int s = 0;
    #pragma unroll
    for (int j = 0; j < 4; ++j) { int g = base + j; if (g < NN) s += cnt[g]; }
    ls[tid] = s; __syncthreads();
    for (int off = 128; off > 0; off >>= 1) {
        if (tid < off) ls[tid] += ls[tid + off];
        __syncthreads();
    }
    if (tid == 0) bsum[b] = ls[0];
}

// per-1024 scan; block base computed in-kernel from bsum (merged k_bscan)
__global__ __launch_bounds__(256) void k_scan_out(const int* __restrict__ cnt,
                                                  const int* __restrict__ bsum,
                                                  int* __restrict__ rowptr) {
    __shared__ int ls[256];
    __shared__ int sbase;
    int b = blockIdx.x, tid = threadIdx.x;
    if (tid < 64) {
        int w0 = (tid < b) ? bsum[tid] : 0;
        int w1 = ((64 + tid) < b) ? bsum[64 + tid] : 0;
        int s = w0 + w1;
        #pragma unroll
        for (int m = 32; m >= 1; m >>= 1) s += __shfl_xor(s, m, 64);
        if (tid == 0) sbase = s;
    }
    int base = b * 1024 + tid * 4;
    int c[4]; int s = 0;
    #pragma unroll
    for (int j = 0; j < 4; ++j) {
        int g = base + j;
        c[j] = (g < NN) ? cnt[g] : 0;
        s += c[j];
    }
    ls[tid] = s; __syncthreads();
    for (int off = 1; off < 256; off <<= 1) {
        int v = (tid >= off) ? ls[tid - off] : 0;
        __syncthreads();
        ls[tid] += v;
        __syncthreads();
    }
    int excl = ls[tid] - s + sbase;
    #pragma unroll
    for (int j = 0; j < 4; ++j) {
        int g = base + j;
        if (g < NN) {
            rowptr[g + 1] = excl + c[j];
            excl += c[j];
        }
    }
    if (b == 0 && tid == 0) rowptr[0] = 0;
}

__global__ __launch_bounds__(256) void k_fill(const int* __restrict__ ei,
                                              const float* __restrict__ ew,
                                              const int* __restrict__ slot,
                                              const int* __restrict__ rowptr,
                                              long long* __restrict__ epair) {
    int e = blockIdx.x * 256 + threadIdx.x;
    if (e >= EE) return;
    int s = __builtin_nontemporal_load(&ei[e]);
    int d = __builtin_nontemporal_load(&ei[EE + e]);
    float w = __builtin_nontemporal_load(&ew[e]);
    int sl = __builtin_nontemporal_load(&slot[e]);
    int p = rowptr[d] + sl;
    long long packed = (unsigned)s | ((long long)__float_as_int(w) << 32);
    __builtin_nontemporal_store(packed, &epair[p]);
}

// deg[n] = 1 + sum_row ew -> dinv[n], xd[n] = dinv[n]*x[n].  4 nodes/wave.
__global__ __launch_bounds__(256) void k_deg(const int* __restrict__ rowptr,
                                             const int2* __restrict__ epair,
                                             const float* __restrict__ x,
                                             float* __restrict__ dinv,
                                             float* __restrict__ xd) {
    int lane = threadIdx.x & 63;
    int wid  = threadIdx.x >> 6;
    int l16  = lane & 15;
    int sub  = lane >> 4;
    int node = (blockIdx.x * 4 + wid) * 4 + sub;
    if (node >= NN) return;
    int beg = rowptr[node], end = rowptr[node + 1];
    float s = 0.f;
    for (int idx = beg + l16; idx < end; idx += 16)
        s += __int_as_float(epair[idx].y);
    #pragma unroll
    for (int m = 8; m >= 1; m >>= 1) s += __shfl_xor(s, m, 64);
    if (l16 == 0) {
        float di = rsqrtf(s + 1.0f);
        dinv[node] = di;
        xd[node] = di * x[node];
    }
}

// ---------------- Layers ----------------
// Identity: Agg_l[d] = dinv_d * ( G'_l[d] + sum_e w_e * G'_l[src] ), G' = dinv (.) G.
// G' AND Y stored bf16 (rows = 32 uints = 128 B). All accumulation fp32.

// Layer 1: z scalar agg + matvec, W2 via LDS. grid NN/16.
__global__ __launch_bounds__(256) void k_l1(
    const float* __restrict__ xd, const float* __restrict__ dinv,
    const int* __restrict__ rowptr, const int2* __restrict__ ep,
    const float* __restrict__ W1, const float* __restrict__ b1,
    const float* __restrict__ W2, unsigned short* __restrict__ Gout)
{
    __shared__ float sW[4096];
    int tid = threadIdx.x;
    #pragma unroll
    for (int i = 0; i < 16; ++i) sW[tid + i * 256] = W2[tid + i * 256];
    __syncthreads();
    int lane = tid & 63, l16 = lane & 15, sub = lane >> 4;
    int g4 = blockIdx.x * 4 + (tid >> 6);
    int nodeS = g4 * 4 + sub;
    int beg = rowptr[nodeS], end = rowptr[nodeS + 1];
    float partial = 0.f;
    for (int idx = beg + l16; idx < end; idx += 16) {
        int2 p = ep[idx];
        partial = fmaf(__int_as_float(p.y), xd[p.x], partial);
    }
    #pragma unroll
    for (int m = 8; m >= 1; m >>= 1) partial += __shfl_xor(partial, m, 64);
    float z = dinv[nodeS] * (xd[nodeS] + partial);   // valid where l16==0
    float z0 = RLF(z, 0), z1 = RLF(z, 16), z2 = RLF(z, 32), z3 = RLF(z, 48);
    float w1l = W1[lane], b1l = b1[lane];
    float v0 = fmaxf(fmaf(z0, w1l, b1l), 0.f);
    float v1 = fmaxf(fmaf(z1, w1l, b1l), 0.f);
    float v2 = fmaxf(fmaf(z2, w1l, b1l), 0.f);
    float v3 = fmaxf(fmaf(z3, w1l, b1l), 0.f);
    float a0 = 0.f, a1 = 0.f, a2 = 0.f, a3 = 0.f;
    #pragma unroll
    for (int k = 0; k < 64; ++k) {
        float wk = sW[k * 64 + lane];
        a0 = fmaf(RLF(v0, k), wk, a0);
        a1 = fmaf(RLF(v1, k), wk, a1);
        a2 = fmaf(RLF(v2, k), wk, a2);
        a3 = fmaf(RLF(v3, k), wk, a3);
    }
    int n0 = g4 * 4;
    Gout[(n0 + 0) * 64 + lane] = bf16rtn(dinv[n0 + 0] * a0);
    Gout[(n0 + 1) * 64 + lane] = bf16rtn(dinv[n0 + 1] * a1);
    Gout[(n0 + 2) * 64 + lane] = bf16rtn(dinv[n0 + 2] * a2);
    Gout[(n0 + 3) * 64 + lane] = bf16rtn(dinv[n0 + 3] * a3);
}

// Gather over bf16 rows (half-wave shape — best of SEVEN measured structures):
// one wave per node; 16-edge batches = 8 row-loads in flight, 2 edges per
// dword load (wave halves); ep indices wave-uniform -> s_load; masked tail
// clamps to ep[j]. Y output bf16 (packed uint per column pair). grid = NN/4.
__global__ __launch_bounds__(256) void k_gather(
    const unsigned* __restrict__ G16, const float* __restrict__ dinv,
    const int* __restrict__ rowptr, const int2* __restrict__ ep,
    unsigned* __restrict__ Yh)
{
    int tid = threadIdx.x;
    int lane = tid & 63;
    int lc = lane & 31;
    int half = lane >> 5;
    int node = blockIdx.x * 4 + (tid >> 6);
    int beg = __builtin_amdgcn_readfirstlane(rowptr[node]);
    int end = __builtin_amdgcn_readfirstlane(rowptr[node + 1]);
    float ax = 0.f, ay = 0.f;
    if (half == 0) {
        unsigned u = G16[node * 32 + lc];
        ax = bflo(u); ay = bfhi(u);
    }
    int j = beg;
    for (; j + 16 <= end; j += 16) {          // full batch: 16 edges, 8 loads
        unsigned u[8]; float nv[8];
        #pragma unroll
        for (int t = 0; t < 8; ++t) {
            int2 pa = ep[j + t];              // uniform -> s_load
            int2 pb = ep[j + 8 + t];          // uniform -> s_load
            int src = half ? pb.x : pa.x;
            nv[t] = __int_as_float(half ? pb.y : pa.y);
            u[t] = G16[src * 32 + lc];
        }
        #pragma unroll
        for (int t = 0; t < 8; ++t) {
            ax = fmaf(bflo(u[t]), nv[t], ax);
            ay = fmaf(bfhi(u[t]), nv[t], ay);
        }
    }
    if (j < end) {                            // masked batch (tail 1..15)
        unsigned u[8]; float nv[8];
        #pragma unroll
        for (int t = 0; t < 8; ++t) {
            int ia = j + t, ib = j + 8 + t;   // uniform
            int2 pa = ep[ia < end ? ia : j];
            int2 pb = ep[ib < end ? ib : j];
            int src = half ? pb.x : pa.x;
            float w = __int_as_float(half ? pb.y : pa.y);
            bool v = half ? (ib < end) : (ia < end);
            nv[t] = v ? w : 0.f;
            u[t] = G16[src * 32 + lc];
        }
        #pragma unroll
        for (int t = 0; t < 8; ++t) {
            ax = fmaf(bflo(u[t]), nv[t], ax);
            ay = fmaf(bfhi(u[t]), nv[t], ay);
        }
    }
    ax += __shfl_xor(ax, 32, 64);
    ay += __shfl_xor(ay, 32, 64);
    if (half == 0) {
        float din = dinv[node];
        Yh[node * 32 + lc] = bf16rtn2(din * ax, din * ay);
    }
}

// G' = dinv (.) ( relu(Y + bias) @ W ), bf16 in/out — 4 nodes/wave, W in VGPRs
// (no preceding memory loop -> safe from demotion, R2/R4 lesson). grid NN/16.
__global__ __launch_bounds__(256, 4) void k_mv(
    const unsigned short* __restrict__ Yh, const float* __restrict__ dinv,
    const float* __restrict__ bias, const float* __restrict__ W,
    unsigned short* __restrict__ Gout)
{
    int lane = threadIdx.x & 63;
    int wid  = threadIdx.x >> 6;
    float w[64];
    #pragma unroll
    for (int k = 0; k < 64; ++k) w[k] = W[k * 64 + lane];
    float bl = bias[lane];
    int n0 = (blockIdx.x * 4 + wid) * 4;
    float v0 = fmaxf(bfs(Yh[(n0 + 0) * 64 + lane]) + bl, 0.f);
    float v1 = fmaxf(bfs(Yh[(n0 + 1) * 64 + lane]) + bl, 0.f);
    float v2 = fmaxf(bfs(Yh[(n0 + 2) * 64 + lane]) + bl, 0.f);
    float v3 = fmaxf(bfs(Yh[(n0 + 3) * 64 + lane]) + bl, 0.f);
    float a0 = 0.f, a1 = 0.f, a2 = 0.f, a3 = 0.f;
    #pragma unroll
    for (int k = 0; k < 64; ++k) {
        float wk = w[k];
        a0 = fmaf(RLF(v0, k), wk, a0);
        a1 = fmaf(RLF(v1, k), wk, a1);
        a2 = fmaf(RLF(v2, k), wk, a2);
        a3 = fmaf(RLF(v3, k), wk, a3);
    }
    Gout[(n0 + 0) * 64 + lane] = bf16rtn(dinv[n0 + 0] * a0);
    Gout[(n0 + 1) * 64 + lane] = bf16rtn(dinv[n0 + 1] * a1);
    Gout[(n0 + 2) * 64 + lane] = bf16rtn(dinv[n0 + 2] * a2);
    Gout[(n0 + 3) * 64 + lane] = bf16rtn(dinv[n0 + 3] * a3);
}

// out = relu(relu(Y+b5)@fW1 + fb1) @ fW2 + fb2 — 4 nodes/wave, fW1 in VGPRs. grid NN/16.
__global__ __launch_bounds__(256, 4) void k_head(
    const unsigned short* __restrict__ Yh, const float* __restrict__ b5,
    const float* __restrict__ fW1, const float* __restrict__ fb1,
    const float* __restrict__ fW2, const float* __restrict__ fb2,
    float* __restrict__ out)
{
    int lane = threadIdx.x & 63;
    int wid  = threadIdx.x >> 6;
    float w[64];
    #pragma unroll
    for (int k = 0; k < 64; ++k) w[k] = fW1[k * 64 + lane];
    float bl = b5[lane], fb1l = fb1[lane], fw2l = fW2[lane], fb2s = fb2[0];
    int n0 = (blockIdx.x * 4 + wid) * 4;
    float v0 = fmaxf(bfs(Yh[(n0 + 0) * 64 + lane]) + bl, 0.f);
    float v1 = fmaxf(bfs(Yh[(n0 + 1) * 64 + lane]) + bl, 0.f);
    float v2 = fmaxf(bfs(Yh[(n0 + 2) * 64 + lane]) + bl, 0.f);
    float v3 = fmaxf(bfs(Yh[(n0 + 3) * 64 + lane]) + bl, 0.f);
    float a0 = 0.f, a1 = 0.f, a2 = 0.f, a3 = 0.f;
    #pragma unroll
    for (int k = 0; k < 64; ++k) {
        float wk = w[k];
        a0 = fmaf(RLF(v0, k), wk, a0);
        a1 = fmaf(RLF(v1, k), wk, a1);
        a2 = fmaf(RLF(v2, k), wk, a2);
        a3 = fmaf(RLF(v3, k), wk, a3);
    }
    float t0 = fmaxf(a0 + fb1l, 0.f) * fw2l;
    float t1 = fmaxf(a1 + fb1l, 0.f) * fw2l;
    float t2 = fmaxf(a2 + fb1l, 0.f) * fw2l;
    float t3 = fmaxf(a3 + fb1l, 0.f) * fw2l;
    #pragma unroll
    for (int m = 32; m >= 1; m >>= 1) {
        t0 += __shfl_xor(t0, m, 64);
        t1 += __shfl_xor(t1, m, 64);
        t2 += __shfl_xor(t2, m, 64);
        t3 += __shfl_xor(t3, m, 64);
    }
    if (lane == 0) {
        out[n0 + 0] = t0 + fb2s;
        out[n0 + 1] = t1 + fb2s;
        out[n0 + 2] = t2 + fb2s;
        out[n0 + 3] = t3 + fb2s;
    }
}

// ---------------- Launch ----------------

extern "C" void kernel_launch(void* const* d_in, const int* in_sizes, int n_in,
                              void* d_out, int out_size, void* d_ws, size_t ws_size,
                              hipStream_t stream) {
    const float* x   = (const float*)d_in[0];
    const int*   ei  = (const int*)d_in[1];
    const float* ew  = (const float*)d_in[2];
    const float* W1  = (const float*)d_in[3];
    const float* b1  = (const float*)d_in[4];
    const float* W2  = (const float*)d_in[5];
    const float* b2  = (const float*)d_in[6];
    const float* W3  = (const float*)d_in[7];
    const float* b3  = (const float*)d_in[8];
    const float* W4  = (const float*)d_in[9];
    const float* b4  = (const float*)d_in[10];
    const float* W5  = (const float*)d_in[11];
    const float* b5  = (const float*)d_in[12];
    const float* fW1 = (const float*)d_in[13];
    const float* fb1 = (const float*)d_in[14];
    const float* fW2 = (const float*)d_in[15];
    const float* fb2 = (const float*)d_in[16];
    float* out = (float*)d_out;

    char* ws = (char*)d_ws;
    size_t o = 0;
    auto alloc = [&](size_t elems) -> void* {
        void* p = (void*)(ws + o);
        o += ((elems * 4 + 255) / 256) * 256;
        return p;
    };
    float* dinv   = (float*)alloc(NN);
    float* xd     = (float*)alloc(NN);
    int*   rowptr = (int*)alloc(NN + 1);
    int*   cnt    = (int*)alloc(NN);
    int*   bsum   = (int*)alloc(128);
    int2*  epair  = (int2*)alloc(2 * (size_t)EE);
    unsigned* Yh   = (unsigned*)alloc((size_t)NN * 32);   // bf16 gather output
    unsigned* Ga16 = (unsigned*)alloc((size_t)NN * 32);   // bf16 feature rows
    unsigned* Gb16 = (unsigned*)alloc((size_t)NN * 32);
    int*   slot   = (int*)alloc(EE);

    int gE  = (EE + 255) / 256;
    int nb  = (NN + 1023) / 1024;    // 98
    int gW1 = NN / 4;                // 25000: 1 node/wave gather
    int gW4 = NN / 16;               // 6250:  4 nodes/wave

    (void)hipMemsetAsync(cnt, 0, NN * sizeof(int), stream);
    k_count<<<gE, 256, 0, stream>>>(ei, cnt, slot);
    k_bsum<<<nb, 256, 0, stream>>>(cnt, bsum);
    k_scan_out<<<nb, 256, 0, stream>>>(cnt, bsum, rowptr);
    k_fill<<<gE, 256, 0, stream>>>(ei, ew, slot, rowptr, (long long*)epair);
    k_deg<<<gW4, 256, 0, stream>>>(rowptr, epair, x, dinv, xd);

    // Layer 1 (scalar gather + matvec) -> G2' bf16
    k_l1<<<gW4, 256, 0, stream>>>(xd, dinv, rowptr, epair, W1, b1, W2,
                                  (unsigned short*)Ga16);
    // Layers 2..4
    k_gather<<<gW1, 256, 0, stream>>>(Ga16, dinv, rowptr, epair, Yh);
    k_mv<<<gW4, 256, 0, stream>>>((unsigned short*)Yh, dinv, b2, W3, (unsigned short*)Gb16);
    k_gather<<<gW1, 256, 0, stream>>>(Gb16, dinv, rowptr, epair, Yh);
    k_mv<<<gW4, 256, 0, stream>>>((unsigned short*)Yh, dinv, b3, W4, (unsigned short*)Ga16);
    k_gather<<<gW1, 256, 0, stream>>>(Ga16, dinv, rowptr, epair, Yh);
    k_mv<<<gW4, 256, 0, stream>>>((unsigned short*)Yh, dinv, b4, W5, (unsigned short*)Gb16);
    // Layer 5 + head
    k_gather<<<gW1, 256, 0, stream>>>(Gb16, dinv, rowptr, epair, Yh);
    k_head<<<gW4, 256, 0, stream>>>((unsigned short*)Yh, b5, fW1, fb1, fW2, fb2, out);
}